// Round 1
// baseline (117.539 us; speedup 1.0000x reference)
//
#include <hip/hip_runtime.h>
#include <math.h>

// Canny front-end, fused: separable 5-tap gaussian (zero-pad per stage),
// sobel x/y, magnitude, early threshold. Output = where(mag < 2, 0, mag).
// The reference's NMS/directional branch is dead code w.r.t. the return value.

#define TW 64
#define TH 32
#define HALO 3                 // 1 (sobel) + 2 (vblur) rows; 1 + 2 (hblur) cols
#define SW (TW + 2 * HALO)     // 70
#define SH (TH + 2 * HALO)     // 38
#define H_IMG 1024
#define W_IMG 1024

__global__ __launch_bounds__(256) void canny_fused(
    const float* __restrict__ img,
    const float* __restrict__ gauss,   // 5 taps: [g0,g1,g2,g1,g0], g2=1.0
    float* __restrict__ out)
{
    __shared__ float s_img[SH][SW];   // raw img tile, zeros outside image
    __shared__ float s_t[SH][SW];     // h-blurred
    __shared__ float s_b[SH][SW];     // fully blurred, zeroed outside image

    const int tx0 = blockIdx.x * TW;
    const int ty0 = blockIdx.y * TH;
    const int b   = blockIdx.z;
    const int tid = threadIdx.x;

    const float g0 = gauss[0];
    const float g1 = gauss[1];
    const float g2 = gauss[2];

    const float* imgb = img + (size_t)b * (H_IMG * W_IMG);

    // ---- stage 0: global -> LDS, zero-padded (exactly the per-conv zero pad) ----
    for (int i = tid; i < SH * SW; i += 256) {
        int sr = i / SW, sc = i - sr * SW;
        int gy = ty0 + sr - HALO;
        int gx = tx0 + sc - HALO;
        float v = 0.0f;
        if (gy >= 0 && gy < H_IMG && gx >= 0 && gx < W_IMG)
            v = imgb[gy * W_IMG + gx];
        s_img[sr][sc] = v;
    }
    __syncthreads();

    // ---- stage 1: horizontal 5-tap blur (all rows; cols [2, SW-3]) ----
    // OOB rows were loaded as 0 -> t=0 there, matching zero-pad of t for vblur.
    for (int i = tid; i < SH * SW; i += 256) {
        int sr = i / SW, sc = i - sr * SW;
        if (sc >= 2 && sc <= SW - 3) {
            s_t[sr][sc] = g0 * (s_img[sr][sc - 2] + s_img[sr][sc + 2])
                        + g1 * (s_img[sr][sc - 1] + s_img[sr][sc + 1])
                        + g2 *  s_img[sr][sc];
        }
    }
    __syncthreads();

    // ---- stage 2: vertical 5-tap blur; zero outside image (zero-pad of
    //      `blurred` as seen by the sobel conv) ----
    for (int i = tid; i < SH * SW; i += 256) {
        int sr = i / SW, sc = i - sr * SW;
        if (sr >= 2 && sr <= SH - 3 && sc >= 2 && sc <= SW - 3) {
            int gy = ty0 + sr - HALO;
            int gx = tx0 + sc - HALO;
            float v = 0.0f;
            if (gy >= 0 && gy < H_IMG && gx >= 0 && gx < W_IMG) {
                v = g0 * (s_t[sr - 2][sc] + s_t[sr + 2][sc])
                  + g1 * (s_t[sr - 1][sc] + s_t[sr + 1][sc])
                  + g2 *  s_t[sr][sc];
            }
            s_b[sr][sc] = v;
        }
    }
    __syncthreads();

    // ---- stage 3: sobel (cross-correlation, as lax/torch conv) + mag + threshold ----
    float* outb = out + (size_t)b * (H_IMG * W_IMG);
    for (int j = tid; j < TH * TW; j += 256) {
        int ly = j / TW, lx = j - ly * TW;   // TW=64: ly=j>>6, lx=j&63, full-row coalesced store
        int sr = ly + HALO, sc = lx + HALO;
        float tl = s_b[sr - 1][sc - 1], tm = s_b[sr - 1][sc], tr = s_b[sr - 1][sc + 1];
        float ml = s_b[sr    ][sc - 1],                       mr = s_b[sr    ][sc + 1];
        float bl = s_b[sr + 1][sc - 1], bm = s_b[sr + 1][sc], br = s_b[sr + 1][sc + 1];
        // sobel_h = [[1,0,-1],[2,0,-2],[1,0,-1]]
        float gx = (tl - tr) + 2.0f * (ml - mr) + (bl - br);
        // sobel_v = sobel_h^T = [[1,2,1],[0,0,0],[-1,-2,-1]]
        float gy = (tl + 2.0f * tm + tr) - (bl + 2.0f * bm + br);
        float mag = sqrtf(gx * gx + gy * gy);
        outb[(ty0 + ly) * W_IMG + (tx0 + lx)] = (mag < 2.0f) ? 0.0f : mag;
    }
}

extern "C" void kernel_launch(void* const* d_in, const int* in_sizes, int n_in,
                              void* d_out, int out_size, void* d_ws, size_t ws_size,
                              hipStream_t stream) {
    const float* img   = (const float*)d_in[0];
    const float* gauss = (const float*)d_in[1];   // gauss_h taps (5 floats)
    float* out = (float*)d_out;
    const int N = in_sizes[0] / (H_IMG * W_IMG);  // = 8

    dim3 grid(W_IMG / TW, H_IMG / TH, N);         // (16, 32, 8) = 4096 blocks
    canny_fused<<<grid, 256, 0, stream>>>(img, gauss, out);
}

// Round 2
// 111.681 us; speedup vs baseline: 1.0525x; 1.0525x over previous
//
#include <hip/hip_runtime.h>
#include <math.h>

// Canny front-end, fused + fully float4-vectorized.
// Pipeline: 5-tap h-blur -> 5-tap v-blur (zero-pad per conv stage) -> sobel
// -> magnitude -> early threshold. NMS branch of the reference is dead code.
//
// Tile 64x32 outputs per 256-thread block. Horizontal halo padded 3->4 so the
// LDS tile is 18 aligned float4 per row (SW=72). Two LDS buffers; the blurred
// tile overwrites the raw tile (dead after h-blur). All LDS traffic is b128.

#define TW 64
#define TH 32
#define HX 4                   // horizontal halo (3 needed, 4 for alignment)
#define HY 3                   // vertical halo
#define SW (TW + 2 * HX)       // 72 floats
#define SH (TH + 2 * HY)       // 38 rows
#define NB (SW / 4)            // 18 float4 per row
#define H_IMG 1024
#define W_IMG 1024

#define SOB(tl, tm, tr, ml, mr, bl, bm, br, dst)                      \
    {                                                                 \
        float gx_ = (tl - tr) + 2.0f * (ml - mr) + (bl - br);         \
        float gy_ = (tl + 2.0f * tm + tr) - (bl + 2.0f * bm + br);    \
        float mag_ = sqrtf(gx_ * gx_ + gy_ * gy_);                    \
        dst = (mag_ < 2.0f) ? 0.0f : mag_;                            \
    }

__global__ __launch_bounds__(256) void canny_fused_v4(
    const float* __restrict__ img,
    const float* __restrict__ gauss,   // 5 taps [g0,g1,g2,g1,g0]
    float* __restrict__ out)
{
    __shared__ float4 s_a[SH][NB];   // raw tile; later reused for blurred tile
    __shared__ float4 s_t[SH][NB];   // h-blurred tile

    const int tx0 = blockIdx.x * TW;
    const int ty0 = blockIdx.y * TH;
    const int b   = blockIdx.z;
    const int tid = threadIdx.x;

    const float g0 = gauss[0];
    const float g1 = gauss[1];
    const float g2 = gauss[2];

    const float* imgb = img + (size_t)b * (H_IMG * W_IMG);
    const float4 zero4 = make_float4(0.0f, 0.0f, 0.0f, 0.0f);

    // ---- stage 0: global -> LDS raw tile (float4, zero outside image) ----
    // Whole-vector bounds: gx0 is a multiple of 4 and W is a multiple of 4,
    // so each float4 is entirely in or out of the image horizontally.
    #pragma unroll
    for (int i = tid; i < SH * NB; i += 256) {      // 684 -> 3 iters
        int r = i / NB, j = i - r * NB;
        int gy  = ty0 + r - HY;
        int gx0 = tx0 + 4 * j - HX;
        float4 v = zero4;
        if (gy >= 0 && gy < H_IMG && gx0 >= 0 && gx0 < W_IMG)
            v = *(const float4*)(imgb + gy * W_IMG + gx0);
        s_a[r][j] = v;
    }
    __syncthreads();

    // ---- stage 1: horizontal 5-tap blur, b128 reads + register shuffle ----
    // Edge blocks (j=0 left / j=NB-1 right) substitute zeros; the affected
    // t-columns {0,1,2} and {69,70,71} are never consumed downstream.
    #pragma unroll
    for (int i = tid; i < SH * NB; i += 256) {      // 684 -> 3 iters
        int r = i / NB, j = i - r * NB;
        float4 A = (j > 0)      ? s_a[r][j - 1] : zero4;
        float4 B = s_a[r][j];
        float4 C = (j < NB - 1) ? s_a[r][j + 1] : zero4;
        float4 t;
        t.x = g0 * (A.z + B.z) + g1 * (A.w + B.y) + g2 * B.x;
        t.y = g0 * (A.w + B.w) + g1 * (B.x + B.z) + g2 * B.y;
        t.z = g0 * (B.x + C.x) + g1 * (B.y + B.w) + g2 * B.z;
        t.w = g0 * (B.y + C.y) + g1 * (B.z + C.x) + g2 * B.w;
        s_t[r][j] = t;
    }
    __syncthreads();

    // ---- stage 2: vertical 5-tap blur; zero outside image (the zero-pad of
    //      `blurred` that sobel's SAME conv sees). Writes over s_a (dead). ----
    #pragma unroll
    for (int i = tid; i < (SH - 4) * NB; i += 256) { // rows 2..35, 612 -> 3 iters
        int r2 = i / NB, j = i - r2 * NB;
        int r = r2 + 2;
        float4 a = s_t[r - 2][j];
        float4 bb = s_t[r - 1][j];
        float4 c = s_t[r][j];
        float4 d = s_t[r + 1][j];
        float4 e = s_t[r + 2][j];
        float4 v;
        v.x = g0 * (a.x + e.x) + g1 * (bb.x + d.x) + g2 * c.x;
        v.y = g0 * (a.y + e.y) + g1 * (bb.y + d.y) + g2 * c.y;
        v.z = g0 * (a.z + e.z) + g1 * (bb.z + d.z) + g2 * c.z;
        v.w = g0 * (a.w + e.w) + g1 * (bb.w + d.w) + g2 * c.w;
        int gy  = ty0 + r - HY;
        int gx0 = tx0 + 4 * j - HX;
        if (!(gy >= 0 && gy < H_IMG && gx0 >= 0 && gx0 < W_IMG)) v = zero4;
        s_a[r][j] = v;   // s_a now holds the blurred tile
    }
    __syncthreads();

    // ---- stage 3: sobel + magnitude + threshold, float4 out ----
    float* outb = out + (size_t)b * (H_IMG * W_IMG);
    #pragma unroll
    for (int i = tid; i < TH * (TW / 4); i += 256) { // 512 -> 2 iters
        int orow = i >> 4;            // 0..31
        int oj   = i & 15;            // 0..15 (output float4 within row)
        int r = orow + HY;            // local row of output
        // window columns 4*oj+3 .. 4*oj+8  ->  blocks oj (.w), oj+1, oj+2 (.x)
        float4 Lt = s_a[r - 1][oj], Mt = s_a[r - 1][oj + 1], Rt = s_a[r - 1][oj + 2];
        float4 Lm = s_a[r    ][oj], Mm = s_a[r    ][oj + 1], Rm = s_a[r    ][oj + 2];
        float4 Lb = s_a[r + 1][oj], Mb = s_a[r + 1][oj + 1], Rb = s_a[r + 1][oj + 2];
        float4 o;
        SOB(Lt.w, Mt.x, Mt.y,  Lm.w, Mm.y,  Lb.w, Mb.x, Mb.y, o.x);
        SOB(Mt.x, Mt.y, Mt.z,  Mm.x, Mm.z,  Mb.x, Mb.y, Mb.z, o.y);
        SOB(Mt.y, Mt.z, Mt.w,  Mm.y, Mm.w,  Mb.y, Mb.z, Mb.w, o.z);
        SOB(Mt.z, Mt.w, Rt.x,  Mm.z, Rm.x,  Mb.z, Mb.w, Rb.x, o.w);
        *(float4*)(outb + (ty0 + orow) * W_IMG + tx0 + 4 * oj) = o;
    }
}

extern "C" void kernel_launch(void* const* d_in, const int* in_sizes, int n_in,
                              void* d_out, int out_size, void* d_ws, size_t ws_size,
                              hipStream_t stream) {
    const float* img   = (const float*)d_in[0];
    const float* gauss = (const float*)d_in[1];
    float* out = (float*)d_out;
    const int N = in_sizes[0] / (H_IMG * W_IMG);   // = 8

    dim3 grid(W_IMG / TW, H_IMG / TH, N);          // (16, 32, 8) = 4096 blocks
    canny_fused_v4<<<grid, 256, 0, stream>>>(img, gauss, out);
}

// Round 3
// 100.925 us; speedup vs baseline: 1.1646x; 1.1066x over previous
//
#include <hip/hip_runtime.h>
#include <math.h>

// Canny front-end, LDS-free register-streaming version.
// Each thread owns one float4 column (4 px wide) and slides down an R-row
// strip, holding rolling register windows: 5 rows of h-blurred values
// (6 floats: cols 4j-1..4j+4) and 3 rows of fully-blurred values.
// Horizontal neighbors come from overlapping global float4 loads (L1/L2
// absorb the 3x overlap). Zero LDS, zero barriers -> no stage serialization.
//
// Semantics preserved per reference: h-conv zero-pads columns of img,
// v-conv zero-pads rows of t, sobel zero-pads rows AND columns of blurred
// (blurred col -1 / col 1024 are zeroed explicitly at the edge threads).

#define H_IMG 1024
#define W_IMG 1024
#define W4 (W_IMG / 4)   // 256 float4 columns = one block spans full width
#define R 8              // output rows per strip; window = R+6 = 14 rows

__global__ __launch_bounds__(256) void canny_stream(
    const float* __restrict__ img,
    const float* __restrict__ gauss,   // 5 taps [g0,g1,g2,g1,g0]
    float* __restrict__ out)
{
    const int j  = threadIdx.x;            // float4 column index 0..255
    const int y0 = blockIdx.x * R;         // first output row of this strip
    const int b  = blockIdx.y;             // image index

    const float g0 = gauss[0], g1 = gauss[1], g2 = gauss[2];
    const float* __restrict__ imgb = img + (size_t)b * (H_IMG * W_IMG);
    float* __restrict__ outb       = out + (size_t)b * (H_IMG * W_IMG);
    const int xc = 4 * j;

    float hb[5][6];   // h-blurred rows, cols xc-1..xc+4 ; row (y0-3+it) at slot it%5
    float bl[3][6];   // blurred rows                    ; row (y0-5+it) at slot (it-4)%3

    #pragma unroll
    for (int it = 0; it < R + 6; ++it) {
        // ---- ingest raw row ry, h-blur into window ----
        const int ry = y0 - 3 + it;
        float* h = hb[it % 5];
        if (ry >= 0 && ry < H_IMG) {
            const float* p = imgb + ry * W_IMG + xc;
            float4 A = make_float4(0.f, 0.f, 0.f, 0.f);
            float4 C = make_float4(0.f, 0.f, 0.f, 0.f);
            if (j > 0)      A = *(const float4*)(p - 4);   // cols xc-4..xc-1
            float4 B = *(const float4*)(p);                // cols xc  ..xc+3
            if (j < W4 - 1) C = *(const float4*)(p + 4);   // cols xc+4..xc+7
            h[0] = g0 * (A.y + B.y) + g1 * (A.z + B.x) + g2 * A.w;  // col xc-1
            h[1] = g0 * (A.z + B.z) + g1 * (A.w + B.y) + g2 * B.x;  // col xc
            h[2] = g0 * (A.w + B.w) + g1 * (B.x + B.z) + g2 * B.y;  // col xc+1
            h[3] = g0 * (B.x + C.x) + g1 * (B.y + B.w) + g2 * B.z;  // col xc+2
            h[4] = g0 * (B.y + C.y) + g1 * (B.z + C.x) + g2 * B.w;  // col xc+3
            h[5] = g0 * (B.z + C.z) + g1 * (B.w + C.y) + g2 * C.x;  // col xc+4
        } else {
            #pragma unroll
            for (int k = 0; k < 6; ++k) h[k] = 0.0f;   // v-conv zero-pad of t rows
        }

        // ---- v-blur: once 5 hb rows live, produce blurred row by = ry-2 ----
        if (it >= 4) {
            const int by = ry - 2;
            float* o = bl[(it - 4) % 3];
            if (by >= 0 && by < H_IMG) {
                const float* h0 = hb[(it - 4) % 5];   // t(by-2)
                const float* h1 = hb[(it - 3) % 5];   // t(by-1)
                const float* h2 = hb[(it - 2) % 5];   // t(by)
                const float* h3 = hb[(it - 1) % 5];   // t(by+1)
                const float* h4 = hb[(it    ) % 5];   // t(by+2)
                #pragma unroll
                for (int k = 0; k < 6; ++k)
                    o[k] = g0 * (h0[k] + h4[k]) + g1 * (h1[k] + h3[k]) + g2 * h2[k];
                // sobel's zero-pad of blurred COLUMNS:
                if (j == 0)      o[0] = 0.0f;   // blurred col -1
                if (j == W4 - 1) o[5] = 0.0f;   // blurred col 1024
            } else {
                #pragma unroll
                for (int k = 0; k < 6; ++k) o[k] = 0.0f;  // sobel zero-pad of rows
            }
        }

        // ---- sobel + mag + threshold on output row oy = ry-3 ----
        if (it >= 6) {
            const int oy = ry - 3;                       // in [y0, y0+R-1]
            const float* T  = bl[(it - 6) % 3];          // blurred(oy-1)
            const float* M  = bl[(it - 5) % 3];          // blurred(oy)
            const float* Bo = bl[(it - 4) % 3];          // blurred(oy+1)
            float4 o4;
            float* po = (float*)&o4;
            #pragma unroll
            for (int k = 0; k < 4; ++k) {                // out col xc+k -> idx k..k+2
                float gx = (T[k] - T[k + 2]) + 2.0f * (M[k] - M[k + 2]) + (Bo[k] - Bo[k + 2]);
                float gy = (T[k] + 2.0f * T[k + 1] + T[k + 2])
                         - (Bo[k] + 2.0f * Bo[k + 1] + Bo[k + 2]);
                float mag = sqrtf(gx * gx + gy * gy);
                po[k] = (mag < 2.0f) ? 0.0f : mag;
            }
            *(float4*)(outb + oy * W_IMG + xc) = o4;
        }
    }
}

extern "C" void kernel_launch(void* const* d_in, const int* in_sizes, int n_in,
                              void* d_out, int out_size, void* d_ws, size_t ws_size,
                              hipStream_t stream) {
    const float* img   = (const float*)d_in[0];
    const float* gauss = (const float*)d_in[1];
    float* out = (float*)d_out;
    const int N = in_sizes[0] / (H_IMG * W_IMG);   // = 8

    dim3 grid(H_IMG / R, N);                       // (128, 8) = 1024 blocks
    canny_stream<<<grid, 256, 0, stream>>>(img, gauss, out);
}